// Round 5
// baseline (511.964 us; speedup 1.0000x reference)
//
#include <hip/hip_runtime.h>
#include <hip/hip_bf16.h>
#include <cstdint>
#include <type_traits>

typedef __attribute__((ext_vector_type(8))) __bf16 bf16x8;
typedef __attribute__((ext_vector_type(8))) short short8;
typedef __attribute__((ext_vector_type(4))) float f32x4;
using u16 = unsigned short;

// ---- MFMA fragment-type autodetect ----
template <typename T, typename = void> struct mfma_ok : std::false_type {};
template <typename T>
struct mfma_ok<T, std::void_t<decltype(__builtin_amdgcn_mfma_f32_16x16x32_bf16(
    std::declval<T>(), std::declval<T>(), std::declval<f32x4>(), 0, 0, 0))>>
    : std::true_type {};
using frag_t = std::conditional_t<mfma_ok<bf16x8>::value, bf16x8, short8>;
static_assert(sizeof(frag_t) == 16, "frag must be 4 VGPRs");

template <typename T>
__device__ __forceinline__ f32x4 MFMA(T a, T b, f32x4 c) {
  return __builtin_amdgcn_mfma_f32_16x16x32_bf16(a, b, c, 0, 0, 0);
}

__device__ __forceinline__ void gl_lds16(const u16* g, u16* l) {
  __builtin_amdgcn_global_load_lds(
      (const __attribute__((address_space(1))) unsigned int*)g,
      (__attribute__((address_space(3))) unsigned int*)l, 16, 0, 0);
}

__device__ __forceinline__ u16 f2bf(float v) {
  __hip_bfloat16 h = __float2bfloat16(v);
  return __builtin_bit_cast(u16, h);
}

// bijective XCD swizzle (nwg % 8 == 0 for all our grids)
__device__ __forceinline__ int xcd_swz(int wid, int nwg) {
  return (wid & 7) * (nwg >> 3) + (wid >> 3);
}

// ---------------------------------------------------------------------------
// GEMM core v5: 256x256(virtual) tile, BK=64, 512 threads / 8 waves (2M x 4N).
// Per-wave output 128 rows x 64 vcols -> acc[8][4]. LDS: 2 x 64KB dbuf.
// m201-style fine phases: 4 phases per K-tile, each
//   {ds_read new quadrant frags | stage 0-4 gl_lds of tile t+1}
//   s_barrier ; setprio(1) 16 MFMA setprio(0) ; s_barrier
// Quadrant order Q00->Q01->Q11->Q10 (zigzag reg reuse). All 8 stage slots of
// tile t+1 issued in phases 0-1; single vmcnt(0) at tile boundary (loads stay
// in flight across the intra-tile barriers).
// Bank swizzle: LDS[row][p] holds global chunk p^(row&7); applied to the
// global source addr (LDS dest linear) and the ds_read offset.
// A[row][k] row-major (lda); B[vcol][k] row-major (ldb). K%128==0 assumed even
// tile count (all our K: 1024, 128, 1408).
// ---------------------------------------------------------------------------
__device__ __forceinline__ void gemm256(
    const u16* __restrict__ A, int lda,
    const u16* __restrict__ B, int ldb, int K,
    u16* lds, f32x4 (&acc)[8][4])
{
  const int t = threadIdx.x;
  const int l = t & 63;
  const int w = t >> 6;
  const int wm = w >> 2, wc = w & 3;

  // staging: thread t covers row t>>3, swizzled chunk
  const int sc = (t & 7) ^ ((t >> 3) & 7);
  const u16* gA = A + (t >> 3) * lda + sc * 8;
  const u16* gB = B + (t >> 3) * ldb + sc * 8;

  // fragment read offsets (swizzle reduces to lane constants)
  const int lr = l & 15;
  const int lk = l >> 4;
  const int lx = l & 7;
  const int pk0 = ((0 + lk) ^ lx) * 8;
  const int pk1 = ((4 + lk) ^ lx) * 8;
  const int arow0 = (wm * 128 + lr) * 64;
  const int brow0 = 16384 + (wc * 64 + lr) * 64;

  const int nt = K >> 6;

#define STAGE_A(buf, kt) do {                                  \
    const u16* a_ = gA + (kt) * 64;                            \
    u16* s_ = (buf);                                           \
    gl_lds16(a_,             s_ + w * 512);                    \
    gl_lds16(a_ +  64 * lda, s_ +  4096 + w * 512);            \
    gl_lds16(a_ + 128 * lda, s_ +  8192 + w * 512);            \
    gl_lds16(a_ + 192 * lda, s_ + 12288 + w * 512);            \
  } while (0)
#define STAGE_B(buf, kt) do {                                  \
    const u16* b_ = gB + (kt) * 64;                            \
    u16* s_ = (buf);                                           \
    gl_lds16(b_,             s_ + 16384 + w * 512);            \
    gl_lds16(b_ +  64 * ldb, s_ + 20480 + w * 512);            \
    gl_lds16(b_ + 128 * ldb, s_ + 24576 + w * 512);            \
    gl_lds16(b_ + 192 * ldb, s_ + 28672 + w * 512);            \
  } while (0)

  // prologue: stage tile 0, drain, barrier
  STAGE_A(lds, 0);
  STAGE_B(lds, 0);
  asm volatile("s_waitcnt vmcnt(0)" ::: "memory");
  __builtin_amdgcn_s_barrier();

  for (int kt = 0; kt < nt; ++kt) {
    u16* cur = lds + (kt & 1) * 32768;
    u16* nxt = lds + ((kt + 1) & 1) * 32768;
    const bool more = (kt + 1 < nt);

    frag_t aL[8], aH[8], bL[4], bH[4];

    // ---- P0: read aL + bL ; stage A(t+1) ; MFMA Q00 (m0-3 x n0-1) ----
#pragma unroll
    for (int fm = 0; fm < 4; ++fm) {
      aL[2 * fm]     = *(const frag_t*)(cur + arow0 + fm * 1024 + pk0);
      aL[2 * fm + 1] = *(const frag_t*)(cur + arow0 + fm * 1024 + pk1);
    }
#pragma unroll
    for (int fn = 0; fn < 2; ++fn) {
      bL[2 * fn]     = *(const frag_t*)(cur + brow0 + fn * 1024 + pk0);
      bL[2 * fn + 1] = *(const frag_t*)(cur + brow0 + fn * 1024 + pk1);
    }
    if (more) STAGE_A(nxt, kt + 1);
    __builtin_amdgcn_s_barrier();
    __builtin_amdgcn_s_setprio(1);
#pragma unroll
    for (int fn = 0; fn < 2; ++fn)
#pragma unroll
      for (int fm = 0; fm < 4; ++fm)
#pragma unroll
        for (int kf = 0; kf < 2; ++kf)
          acc[fm][fn] = MFMA(aL[2 * fm + kf], bL[2 * fn + kf], acc[fm][fn]);
    __builtin_amdgcn_s_setprio(0);
    __builtin_amdgcn_s_barrier();

    // ---- P1: read bH ; stage B(t+1) ; MFMA Q01 (m0-3 x n2-3) ----
#pragma unroll
    for (int fn = 0; fn < 2; ++fn) {
      bH[2 * fn]     = *(const frag_t*)(cur + brow0 + (fn + 2) * 1024 + pk0);
      bH[2 * fn + 1] = *(const frag_t*)(cur + brow0 + (fn + 2) * 1024 + pk1);
    }
    if (more) STAGE_B(nxt, kt + 1);
    __builtin_amdgcn_s_barrier();
    __builtin_amdgcn_s_setprio(1);
#pragma unroll
    for (int fn = 0; fn < 2; ++fn)
#pragma unroll
      for (int fm = 0; fm < 4; ++fm)
#pragma unroll
        for (int kf = 0; kf < 2; ++kf)
          acc[fm][fn + 2] =
              MFMA(aL[2 * fm + kf], bH[2 * fn + kf], acc[fm][fn + 2]);
    __builtin_amdgcn_s_setprio(0);
    __builtin_amdgcn_s_barrier();

    // ---- P2: read aH ; MFMA Q11 (m4-7 x n2-3) ----
#pragma unroll
    for (int fm = 0; fm < 4; ++fm) {
      aH[2 * fm]     = *(const frag_t*)(cur + arow0 + (fm + 4) * 1024 + pk0);
      aH[2 * fm + 1] = *(const frag_t*)(cur + arow0 + (fm + 4) * 1024 + pk1);
    }
    __builtin_amdgcn_s_barrier();
    __builtin_amdgcn_s_setprio(1);
#pragma unroll
    for (int fn = 0; fn < 2; ++fn)
#pragma unroll
      for (int fm = 0; fm < 4; ++fm)
#pragma unroll
        for (int kf = 0; kf < 2; ++kf)
          acc[fm + 4][fn + 2] =
              MFMA(aH[2 * fm + kf], bH[2 * fn + kf], acc[fm + 4][fn + 2]);
    __builtin_amdgcn_s_setprio(0);
    __builtin_amdgcn_s_barrier();

    // ---- P3: no reads ; MFMA Q10 (m4-7 x n0-1) ; tile boundary ----
    __builtin_amdgcn_s_setprio(1);
#pragma unroll
    for (int fn = 0; fn < 2; ++fn)
#pragma unroll
      for (int fm = 0; fm < 4; ++fm)
#pragma unroll
        for (int kf = 0; kf < 2; ++kf)
          acc[fm + 4][fn] =
              MFMA(aH[2 * fm + kf], bL[2 * fn + kf], acc[fm + 4][fn]);
    __builtin_amdgcn_s_setprio(0);
    if (more) asm volatile("s_waitcnt vmcnt(0)" ::: "memory");
    __builtin_amdgcn_s_barrier();
  }
#undef STAGE_A
#undef STAGE_B
}

// ---------------------------------------------------------------------------
// Kernel 1: weight repack f32 -> bf16 with gate/half interleaving.
// Wint[16 strips][256 vcols][1024]   vcol = wc*64 + gate*16 + c16,
//                                    actual col = s*64 + wc*16 + c16
// Rint[16 strips][256 vcols][128]    same vcol map, col within head
// upint[11 tiles][256 vcols][1024]   vcol = wc*64 + half*32 + c32,
//                                    actual col = tile*128 + wc*32 + c32
// dnp[1024][1408] k-padded zeros
// ---------------------------------------------------------------------------
__global__ __launch_bounds__(256) void prep_kernel(
    const float* __restrict__ Wi, const float* __restrict__ Wf,
    const float* __restrict__ Wz, const float* __restrict__ Wo,
    const float* __restrict__ Ri, const float* __restrict__ Rf,
    const float* __restrict__ Rz, const float* __restrict__ Ro,
    const float* __restrict__ upw, const float* __restrict__ dnw,
    u16* __restrict__ Wint, u16* __restrict__ Rint,
    u16* __restrict__ upint, u16* __restrict__ dnp)
{
  const int stride = gridDim.x * 256;
  for (int i = blockIdx.x * 256 + threadIdx.x; i < 9043968; i += stride) {
    if (i < 4194304) {
      const int s = i >> 18, v = (i >> 10) & 255, k = i & 1023;
      const int wc = v >> 6, gsel = (v >> 4) & 3, c16 = v & 15;
      const int srcRow = s * 64 + wc * 16 + c16;
      const float* W = (gsel == 0) ? Wi : (gsel == 1) ? Wf : (gsel == 2) ? Wz : Wo;
      Wint[i] = f2bf(W[srcRow * 1024 + k]);
    } else if (i < 4718592) {
      const int j = i - 4194304;
      const int s = j >> 15, v = (j >> 7) & 255, k = j & 127;
      const int wc = v >> 6, gsel = (v >> 4) & 3, c16 = v & 15;
      const int head = s >> 1;
      const int colInHead = (s & 1) * 64 + wc * 16 + c16;
      const float* R = (gsel == 0) ? Ri : (gsel == 1) ? Rf : (gsel == 2) ? Rz : Ro;
      Rint[j] = f2bf(R[head * 16384 + colInHead * 128 + k]);
    } else if (i < 7602176) {
      const int j = i - 4718592;
      const int vcol = j >> 10, k = j & 1023;
      const int tile = vcol >> 8, wc = (vcol >> 6) & 3;
      const int half = (vcol >> 5) & 1, c32 = vcol & 31;
      const int a = tile * 128 + wc * 32 + c32;
      upint[j] = (a < 1365) ? f2bf(upw[(half * 1365 + a) * 1024 + k]) : (u16)0;
    } else {
      const int j = i - 7602176;
      const int row = j / 1408, k = j - row * 1408;
      dnp[j] = (k < 1365) ? f2bf(dnw[row * 1365 + k]) : (u16)0;
    }
  }
}

// ---------------------------------------------------------------------------
// Kernel 2: LayerNorm(seq) -> x bf16 ; h0 -> bf16. One row per block.
// ---------------------------------------------------------------------------
__global__ __launch_bounds__(256) void ln_kernel(
    const float* __restrict__ seq, const float* __restrict__ h0,
    const float* __restrict__ lnw, const float* __restrict__ lnb,
    u16* __restrict__ xb, u16* __restrict__ h0b)
{
  const int row = blockIdx.x;
  const int t = threadIdx.x;
  const float4 v = ((const float4*)(seq + (size_t)row * 1024))[t];
  float s = v.x + v.y + v.z + v.w;
  float q = v.x * v.x + v.y * v.y + v.z * v.z + v.w * v.w;
#pragma unroll
  for (int o = 32; o >= 1; o >>= 1) { s += __shfl_xor(s, o); q += __shfl_xor(q, o); }
  __shared__ float sm[8];
  const int l = t & 63, w = t >> 6;
  if (l == 0) { sm[w] = s; sm[4 + w] = q; }
  __syncthreads();
  s = sm[0] + sm[1] + sm[2] + sm[3];
  q = sm[4] + sm[5] + sm[6] + sm[7];
  const float mu = s * (1.f / 1024.f);
  const float var = q * (1.f / 1024.f) - mu * mu;
  const float rstd = rsqrtf(var + 1e-5f);
  const float4 wv = ((const float4*)lnw)[t];
  const float4 bv = ((const float4*)lnb)[t];
  ushort4 o4;
  o4.x = f2bf((v.x - mu) * rstd * wv.x + bv.x);
  o4.y = f2bf((v.y - mu) * rstd * wv.y + bv.y);
  o4.z = f2bf((v.z - mu) * rstd * wv.z + bv.z);
  o4.w = f2bf((v.w - mu) * rstd * wv.w + bv.w);
  ((ushort4*)(xb + (size_t)row * 1024))[t] = o4;
  const float4 h = ((const float4*)(h0 + (size_t)row * 1024))[t];
  ushort4 h4;
  h4.x = f2bf(h.x); h4.y = f2bf(h.y); h4.z = f2bf(h.z); h4.w = f2bf(h.w);
  ((ushort4*)(h0b + (size_t)row * 1024))[t] = h4;
}

// ---------------------------------------------------------------------------
// Kernel 3: fused 4-gate GEMM (+recurrent block-diag) + sLSTM pointwise.
// Block: 256 rows x strip(64 actual cols) x 4 gates (virtual N=256).
// Wave owns 128 rows x 16 actual cols x 4 gates -> pointwise in-register.
// ---------------------------------------------------------------------------
__global__ __launch_bounds__(512, 2) void gate_kernel(
    const u16* __restrict__ xb, const u16* __restrict__ h0b,
    const u16* __restrict__ Wint, const u16* __restrict__ Rint,
    const float* __restrict__ bi, const float* __restrict__ bfv,
    const float* __restrict__ bz, const float* __restrict__ bo,
    const float* __restrict__ c0, const float* __restrict__ n0i,
    const float* __restrict__ m0,
    float* __restrict__ oc, float* __restrict__ on,
    float* __restrict__ oh, float* __restrict__ om)
{
  __shared__ __align__(16) u16 lds[65536];
  const int wid = xcd_swz(blockIdx.x, 1024);
  const int s = wid & 15;           // 64-col strip
  const int m0r = (wid >> 4) * 256;
  f32x4 acc[8][4] = {};
  // x @ W^T (K=1024)
  gemm256(xb + (size_t)m0r * 1024, 1024, Wint + s * 262144, 1024, 1024, lds, acc);
  // + blockdiag(h0 @ R^T) (K=128; strip lies entirely in head s>>1)
  const int head = s >> 1;
  gemm256(h0b + (size_t)m0r * 1024 + head * 128, 1024,
          Rint + s * 32768, 128, 128, lds, acc);

  const int t = threadIdx.x, l = t & 63, w = t >> 6, wm = w >> 2, wc = w & 3;
  const int cc = s * 64 + wc * 16 + (l & 15);
  const float biv = bi[cc], bfvv = bfv[cc], bzv = bz[cc], bov = bo[cc];
#pragma unroll
  for (int fm = 0; fm < 8; ++fm) {
    const int rbase = m0r + wm * 128 + fm * 16 + (l >> 4) * 4;
#pragma unroll
    for (int r = 0; r < 4; ++r) {
      const size_t idx = (size_t)(rbase + r) * 1024 + cc;
      const float it = acc[fm][0][r] + biv;
      const float ft = acc[fm][1][r] + bfvv;
      const float zt = acc[fm][2][r] + bzv;
      const float ot = acc[fm][3][r] + bov;
      const float mp = m0[idx];
      const float mt = fmaxf(ft + mp, it);
      const float ie = __expf(it - mt);
      const float fe = __expf(ft - mt + mp);
      const float ct = fe * c0[idx] + ie * tanhf(zt);
      const float nt = fe * n0i[idx] + ie;
      const float ht = (ct / nt) / (1.f + __expf(-ot));
      oc[idx] = ct; on[idx] = nt; oh[idx] = ht; om[idx] = mt;
    }
  }
}

// ---------------------------------------------------------------------------
// Kernel 4: GroupNorm over heads (128 ch / group), one wave per group -> bf16
// ---------------------------------------------------------------------------
__global__ __launch_bounds__(256) void gn_kernel(
    const float* __restrict__ h, const float* __restrict__ gw,
    const float* __restrict__ gb, u16* __restrict__ gnb)
{
  const int t = threadIdx.x, l = t & 63, w = t >> 6;
  for (int grp = blockIdx.x * 4 + w; grp < 16384 * 8; grp += gridDim.x * 4) {
    const int b = grp >> 3, hd = grp & 7;
    const float2 v = ((const float2*)(h + b * 1024 + hd * 128))[l];
    float s = v.x + v.y, q = v.x * v.x + v.y * v.y;
#pragma unroll
    for (int o = 32; o >= 1; o >>= 1) { s += __shfl_xor(s, o); q += __shfl_xor(q, o); }
    const float mu = s * (1.f / 128.f);
    const float var = q * (1.f / 128.f) - mu * mu;
    const float rstd = rsqrtf(var + 1e-5f);
    const float2 wv = ((const float2*)(gw + hd * 128))[l];
    const float2 bv = ((const float2*)(gb + hd * 128))[l];
    ushort2 o2;
    o2.x = f2bf((v.x - mu) * rstd * wv.x + bv.x);
    o2.y = f2bf((v.y - mu) * rstd * wv.y + bv.y);
    ((ushort2*)(gnb + b * 1024 + hd * 128))[l] = o2;
  }
}

// ---------------------------------------------------------------------------
// Kernel 5: up-proj; halves interleaved so (u1,u2) pair in-wave; GELU-GLU.
// ---------------------------------------------------------------------------
__global__ __launch_bounds__(512, 2) void up_kernel(
    const u16* __restrict__ gnb, const u16* __restrict__ upint,
    const float* __restrict__ upb, u16* __restrict__ g)
{
  __shared__ __align__(16) u16 lds[65536];
  const int wid = xcd_swz(blockIdx.x, 704);
  const int vt = wid % 11, mt = wid / 11;
  const int m0r = mt * 256;
  f32x4 acc[8][4] = {};
  gemm256(gnb + (size_t)m0r * 1024, 1024, upint + vt * 262144, 1024, 1024,
          lds, acc);
  const int t = threadIdx.x, l = t & 63, w = t >> 6, wm = w >> 2, wc = w & 3;
#pragma unroll
  for (int fm = 0; fm < 8; ++fm) {
    const int rbase = m0r + wm * 128 + fm * 16 + (l >> 4) * 4;
#pragma unroll
    for (int fn = 0; fn < 2; ++fn) {
      const int a = vt * 128 + wc * 32 + fn * 16 + (l & 15);
      const float b1 = (a < 1365) ? upb[a] : 0.f;
      const float b2 = (a < 1365) ? upb[1365 + a] : 0.f;
#pragma unroll
      for (int r = 0; r < 4; ++r) {
        const float u1 = acc[fm][fn][r] + b1;
        const float u2 = acc[fm][fn + 2][r] + b2;
        const float ge = 0.5f * u2 * (1.f + erff(u2 * 0.70710678118654752f));
        g[(size_t)(rbase + r) * 1408 + a] = f2bf(u1 + ge);
      }
    }
  }
}

// ---------------------------------------------------------------------------
// Kernel 6: down-proj (K=1408, zero-padded) + bias + residual -> d_out
// ---------------------------------------------------------------------------
__global__ __launch_bounds__(512, 2) void down_kernel(
    const u16* __restrict__ g, const u16* __restrict__ dnp,
    const float* __restrict__ dnb, const float* __restrict__ seq,
    float* __restrict__ out)
{
  __shared__ __align__(16) u16 lds[65536];
  const int wid = xcd_swz(blockIdx.x, 256);
  const int nc = (wid & 3) * 256;
  const int m0r = (wid >> 2) * 256;
  f32x4 acc[8][4] = {};
  gemm256(g + (size_t)m0r * 1408, 1408, dnp + nc * 1408, 1408, 1408, lds, acc);
  const int t = threadIdx.x, l = t & 63, w = t >> 6, wm = w >> 2, wc = w & 3;
#pragma unroll
  for (int fm = 0; fm < 8; ++fm) {
    const int rbase = m0r + wm * 128 + fm * 16 + (l >> 4) * 4;
#pragma unroll
    for (int fn = 0; fn < 4; ++fn) {
      const int cc = nc + wc * 64 + fn * 16 + (l & 15);
      const float bb = dnb[cc];
#pragma unroll
      for (int r = 0; r < 4; ++r) {
        const size_t idx = (size_t)(rbase + r) * 1024 + cc;
        out[idx] = acc[fm][fn][r] + bb + seq[idx];
      }
    }
  }
}

// ---------------------------------------------------------------------------
extern "C" void kernel_launch(void* const* d_in, const int* in_sizes, int n_in,
                              void* d_out, int out_size, void* d_ws, size_t ws_size,
                              hipStream_t stream) {
  const float* seq = (const float*)d_in[0];
  const float* c0  = (const float*)d_in[1];
  const float* n0i = (const float*)d_in[2];
  const float* h0  = (const float*)d_in[3];
  const float* m0  = (const float*)d_in[4];
  const float* lnw = (const float*)d_in[5];
  const float* lnb = (const float*)d_in[6];
  const float* Wz  = (const float*)d_in[7];
  const float* bz  = (const float*)d_in[8];
  const float* Wi  = (const float*)d_in[9];
  const float* bi  = (const float*)d_in[10];
  const float* Wo  = (const float*)d_in[11];
  const float* bo  = (const float*)d_in[12];
  const float* Wf  = (const float*)d_in[13];
  const float* bf_ = (const float*)d_in[14];
  const float* Rz  = (const float*)d_in[15];
  const float* Ri  = (const float*)d_in[16];
  const float* Ro  = (const float*)d_in[17];
  const float* Rf  = (const float*)d_in[18];
  const float* gw  = (const float*)d_in[19];
  const float* gb  = (const float*)d_in[20];
  const float* upw = (const float*)d_in[21];
  const float* upb = (const float*)d_in[22];
  const float* dnw = (const float*)d_in[23];
  const float* dnb = (const float*)d_in[24];

  char* ws = (char*)d_ws;
  u16* xb   = (u16*)(ws);              // 33,554,432 B (reused for gn output)
  u16* h0b  = (u16*)(ws + 33554432);   // 33,554,432 B
  u16* Wint = (u16*)(ws + 67108864);   //  8,388,608 B
  u16* Rint = (u16*)(ws + 75497472);   //  1,048,576 B
  u16* upc  = (u16*)(ws + 76546048);   //  5,767,168 B
  u16* dnp  = (u16*)(ws + 82313216);   //  2,883,584 B
  u16* g    = (u16*)(ws + 85196800);   // 46,137,344 B

  float* out = (float*)d_out;
  float* oc = out + 16777216;
  float* on = out + 2 * 16777216;
  float* oh = out + 3 * 16777216;
  float* om = out + 4 * 16777216;

  prep_kernel<<<dim3(2048), dim3(256), 0, stream>>>(
      Wi, Wf, Wz, Wo, Ri, Rf, Rz, Ro, upw, dnw, Wint, Rint, upc, dnp);
  ln_kernel<<<dim3(16384), dim3(256), 0, stream>>>(seq, h0, lnw, lnb, xb, h0b);
  gate_kernel<<<dim3(1024), dim3(512), 0, stream>>>(
      xb, h0b, Wint, Rint, bi, bf_, bz, bo, c0, n0i, m0, oc, on, oh, om);
  gn_kernel<<<dim3(2048), dim3(256), 0, stream>>>(oh, gw, gb, xb);
  up_kernel<<<dim3(704), dim3(512), 0, stream>>>(xb, upc, upb, g);
  down_kernel<<<dim3(256), dim3(512), 0, stream>>>(g, dnp, dnb, seq, out);
}